// Round 6
// baseline (322.618 us; speedup 1.0000x reference)
//
#include <hip/hip_runtime.h>
#include <math.h>

// Problem constants (fixed by reference)
#define B_ 2
#define S_ 2048
#define E_ 1024
#define H_ 16
#define D_ 64
#define M_ (B_ * S_)
// HEAD_DIM * -0.5 = -32 (faithful source bug) folded with 1/ln2 (exp2-domain
// softmax). Folded into Wk at convert time.
#define SC2 (-46.166241308446828f)

typedef unsigned short u16;
typedef _Float16 f16;
typedef __attribute__((ext_vector_type(8))) _Float16 f16x8;   // 4 VGPRs
typedef __attribute__((ext_vector_type(2))) __fp16 fp16x2_n;  // builtin ret type
typedef __attribute__((ext_vector_type(16))) float f32x16;    // 32x32 MFMA acc

static __device__ __forceinline__ f32x16 mfma_h(f16x8 a, f16x8 b, f32x16 c) {
    return __builtin_amdgcn_mfma_f32_32x32x16_f16(a, b, c, 0, 0, 0);
}
static __device__ __forceinline__ u16 f16bits(f16 h) {
    union { f16 h; u16 u; } c; c.h = h; return c.u;
}
static __device__ __forceinline__ unsigned pack2(u16 a, u16 b) {
    return (unsigned)a | ((unsigned)b << 16);
}
// One v_cvt_pkrtz_f16_f32: packs two floats to two fp16 (RTZ; P in [0,1]).
static __device__ __forceinline__ unsigned pkrtz(float a, float b) {
    fp16x2_n h = __builtin_amdgcn_cvt_pkrtz(a, b);
    unsigned u; __builtin_memcpy(&u, &h, 4); return u;
}
// v_permlane32_swap_b32: new a[32:63] = old b[0:31]; new b[0:31] = old a[32:63].
static __device__ __forceinline__ void pl32swap(unsigned &a, unsigned &b) {
    asm volatile("v_permlane32_swap_b32 %0, %1" : "+v"(a), "+v"(b));
}
#define ROWMAP(r, hh) (((r) & 3) + ((((r) >> 2)) << 3) + ((hh) << 2))

// ============================================================================
// One-shot fp32 -> fp16 hi (+ lo-residual where needed). SC2 folded into Wk.
// x, Wk, Wv: hi+lo. Wo: hi only (final GEMM is hi-only).
// ============================================================================
__global__ __launch_bounds__(256)
void convert_split(const float* __restrict__ x, const float* __restrict__ Wk,
                   const float* __restrict__ Wv, const float* __restrict__ Wo,
                   u16* __restrict__ Xh, u16* __restrict__ Xl,
                   u16* __restrict__ Wkh, u16* __restrict__ Wkl,
                   u16* __restrict__ Wvh, u16* __restrict__ Wvl,
                   u16* __restrict__ Woh)
{
    const int blk = blockIdx.x;
    const float* src; u16 *dh, *dl; int base; float sc = 1.0f; bool wantlo = true;
    if (blk < 4096)      { src = x;  dh = Xh;  dl = Xl;  base = blk; }
    else if (blk < 5120) { src = Wk; dh = Wkh; dl = Wkl; base = blk - 4096; sc = SC2; }
    else if (blk < 6144) { src = Wv; dh = Wvh; dl = Wvl; base = blk - 5120; }
    else                 { src = Wo; dh = Woh; dl = Woh; base = blk - 6144; wantlo = false; }
    const size_t off = ((size_t)base * 256 + threadIdx.x) * 4;
    const float4 v = *(const float4*)(src + off);
    const float f[4] = {v.x * sc, v.y * sc, v.z * sc, v.w * sc};
    u16 h4[4], l4[4];
#pragma unroll
    for (int i = 0; i < 4; ++i) {
        const f16 h = (f16)f[i];
        h4[i] = f16bits(h);
        l4[i] = f16bits((f16)(f[i] - (float)h));
    }
    *(uint2*)(dh + off) = make_uint2(pack2(h4[0], h4[1]), pack2(h4[2], h4[3]));
    if (wantlo)
        *(uint2*)(dl + off) = make_uint2(pack2(l4[0], l4[1]), pack2(l4[2], l4[3]));
}

// ============================================================================
// GEMM C = A @ W^T, 32x32x16 fp16 MFMA, hi/lo fp16 inputs.
// MODE 0: fused K+V projection, 3-pass split each (fp32-grade); outputs
//         Kh/Kl (fp16 hi/lo, SC2 pre-folded), Vh [B,H,S,D], Vt [B,H,D,S].
//         BK=32 (6 staged arrays, LDS-capped).
// MODE 1: O @ Wo^T, hi-only, fp32 out [M,E]. BK=64 (R5 lesson: MODE 1 ran
//         the same 65us as MODE 0 with 6x less work -> round-count-bound;
//         2 arrays allow 33KB staging -> 16 rounds instead of 32).
// 1024 thr / 16 waves, __launch_bounds__(1024,4). Wave layout: 4m x 2n
// quadrants of 32x64 x 2-way K-SPLIT (ws), fp32 merge via LDS. Register
// prefetch of tile k+1. Grid (8,32)=256 blocks = 1/CU.
// ============================================================================
#define CSB 1032            // (128+1)*8 u16 chunk stride (pad -> spread banks)

template<int MODE>
__global__ __launch_bounds__(1024, 4)
void gemm_f(const u16* __restrict__ Ah_, const u16* __restrict__ Al_,
            const u16* __restrict__ Bkh_, const u16* __restrict__ Bkl_,
            const u16* __restrict__ Bvh_, const u16* __restrict__ Bvl_,
            u16* __restrict__ Khg, u16* __restrict__ Klg,
            u16* __restrict__ Vhg, u16* __restrict__ Vtg,
            float* __restrict__ Cout)
{
    constexpr int BK   = (MODE == 0 ? 32 : 64);
    constexpr int ARRX = (BK / 8) * CSB;        // 4128 or 8256 u16
    constexpr int NARR = (MODE == 0 ? 6 : 2);
    constexpr int NIT  = E_ / BK;               // 32 or 16
    constexpr int SSZ  = (NARR * ARRX > 16384 ? NARR * ARRX : 16384);  // >=32KB
    __shared__ u16 stage[SSZ];

    const int tid = threadIdx.x;
    const int w = tid >> 6, l31 = tid & 31, hh = (tid >> 5) & 1;
    const int wt = w & 7, ws = w >> 3;          // 4m x 2n quadrant / k-split half
    const int wm = (wt >> 1) << 5, wn = (wt & 1) << 6;
    const int m0 = blockIdx.y * 128, n0 = blockIdx.x * 128;
    const int ch8 = (ws << 1) + hh;             // this wave-half's k-subchunk

    // staging thread map
    int sr, sch;
    if constexpr (MODE == 0) { sr = (tid & 511) >> 2; sch = tid & 3; }   // +sub
    else                     { sr = tid >> 3;         sch = tid & 7; }
    const int sub = tid >> 9;                   // wave-uniform 0/1 (MODE 0)
    const size_t gA = (size_t)(m0 + sr) * E_ + (sch << 3);
    const size_t gB = (size_t)(n0 + sr) * E_ + (sch << 3);
    const int slo = sch * CSB + sr * 8;

    f32x16 acc1[2], acc2[2];
#pragma unroll
    for (int nt = 0; nt < 2; ++nt)
#pragma unroll
        for (int r = 0; r < 16; ++r) {
            acc1[nt][r] = 0.f;
            if constexpr (MODE == 0) acc2[nt][r] = 0.f;
        }

    constexpr int NPF = (MODE == 0 ? 3 : 2);
    f16x8 pf[NPF];
    auto load_tile = [&](int k0) {
        if constexpr (MODE == 0) {
            pf[0] = *(const f16x8*)((sub ? Al_ : Ah_) + gA + k0);
            pf[1] = *(const f16x8*)((sub ? Bkl_ : Bkh_) + gB + k0);
            pf[2] = *(const f16x8*)((sub ? Bvl_ : Bvh_) + gB + k0);
        } else {
            pf[0] = *(const f16x8*)(Ah_ + gA + k0);
            pf[1] = *(const f16x8*)(Bkh_ + gB + k0);
        }
    };
    auto store_tile = [&]() {
        if constexpr (MODE == 0) {
            *(f16x8*)&stage[(0 + sub) * ARRX + slo] = pf[0];
            *(f16x8*)&stage[(2 + sub) * ARRX + slo] = pf[1];
            *(f16x8*)&stage[(4 + sub) * ARRX + slo] = pf[2];
        } else {
            *(f16x8*)&stage[slo] = pf[0];
            *(f16x8*)&stage[ARRX + slo] = pf[1];
        }
    };

    load_tile(0);
    for (int it = 0; it < NIT; ++it) {
        store_tile();
        __syncthreads();
        if (it + 1 < NIT) load_tile((it + 1) * BK);   // prefetch under compute

        if constexpr (MODE == 0) {
            const int co = ch8 * CSB;
            const int off = co + (wm + l31) * 8;
            const f16x8 xh = *(const f16x8*)&stage[0 * ARRX + off];
            const f16x8 xl = *(const f16x8*)&stage[1 * ARRX + off];
#pragma unroll
            for (int nt = 0; nt < 2; ++nt) {
                const int ro = co + (wn + (nt << 5) + l31) * 8;
                const f16x8 bkh = *(const f16x8*)&stage[2 * ARRX + ro];
                const f16x8 bkl = *(const f16x8*)&stage[3 * ARRX + ro];
                const f16x8 bvh = *(const f16x8*)&stage[4 * ARRX + ro];
                const f16x8 bvl = *(const f16x8*)&stage[5 * ARRX + ro];
                acc1[nt] = mfma_h(xh, bkh, acc1[nt]);
                acc1[nt] = mfma_h(xh, bkl, acc1[nt]);
                acc1[nt] = mfma_h(xl, bkh, acc1[nt]);
                acc2[nt] = mfma_h(xh, bvh, acc2[nt]);
                acc2[nt] = mfma_h(xh, bvl, acc2[nt]);
                acc2[nt] = mfma_h(xl, bvh, acc2[nt]);
            }
        } else {
            // BK=64: wave-half covers chunks {ch8, ch8+4}
#pragma unroll
            for (int kk = 0; kk < 2; ++kk) {
                const int co = (ch8 + (kk << 2)) * CSB;
                const f16x8 xh = *(const f16x8*)&stage[co + (wm + l31) * 8];
#pragma unroll
                for (int nt = 0; nt < 2; ++nt) {
                    const int ro = co + (wn + (nt << 5) + l31) * 8;
                    const f16x8 bh = *(const f16x8*)&stage[ARRX + ro];
                    acc1[nt] = mfma_h(xh, bh, acc1[nt]);
                }
            }
        }
        __syncthreads();   // reads done before next store_tile overwrites
    }

    // K-split merge via LDS (32KB rounds: one (array,nt) per round), ws1 -> ws0.
    float* red = (float*)stage;
    constexpr int NR = (MODE == 0 ? 4 : 2);
#pragma unroll
    for (int rd = 0; rd < NR; ++rd) {
        const int ntr = rd & 1;
        f32x16* A = (MODE == 0 && rd >= 2) ? &acc2[ntr] : &acc1[ntr];
        __syncthreads();
        if (ws == 1) {
#pragma unroll
            for (int r = 0; r < 16; ++r)
                red[(wt << 10) + (r << 6) + (hh << 5) + l31] = (*A)[r];
        }
        __syncthreads();
        if (ws == 0) {
#pragma unroll
            for (int r = 0; r < 16; ++r)
                (*A)[r] += red[(wt << 10) + (r << 6) + (hh << 5) + l31];
        }
    }
    if (ws != 0) return;

    // Epilogue (ws0, 8 waves cover 128x128). C/D map: col=lane&31, row=ROWMAP.
#pragma unroll
    for (int nt = 0; nt < 2; ++nt) {
        const int n = n0 + wn + (nt << 5) + l31;
        if constexpr (MODE == 1) {
#pragma unroll
            for (int r = 0; r < 16; ++r) {
                const int m = m0 + wm + ROWMAP(r, hh);
                Cout[(size_t)m * E_ + n] = acc1[nt][r];
            }
        } else {
            const int hd = n >> 6, d = n & 63;
            const int b = m0 >> 11;             // block never crosses batch
            u16 vb16[16];
#pragma unroll
            for (int r = 0; r < 16; ++r) {
                const int s = (m0 + wm + ROWMAP(r, hh)) & (S_ - 1);
                const size_t ib = (((size_t)(b * H_ + hd) << 11) + s) * D_ + d;
                const float kv = acc1[nt][r];   // SC2 already folded
                const f16 kh = (f16)kv;
                Khg[ib] = f16bits(kh);
                Klg[ib] = f16bits((f16)(kv - (float)kh));
                const f16 vh = (f16)acc2[nt][r];
                vb16[r] = f16bits(vh);
                Vhg[ib] = vb16[r];
            }
            const size_t vtb = ((size_t)(b * H_ + hd) * D_ + d) << 11;
#pragma unroll
            for (int g = 0; g < 4; ++g) {
                const int s0 = ((m0 + wm) & (S_ - 1)) + (g << 3) + (hh << 2);
                *(uint2*)&Vtg[vtb + s0] =
                    make_uint2(pack2(vb16[4 * g], vb16[4 * g + 1]),
                               pack2(vb16[4 * g + 2], vb16[4 * g + 3]));
            }
        }
    }
}

// ============================================================================
// Attention: logits2 = Ks@V^T, base-2 online softmax, O = P@V. All fp16.
// 1024 thr / 16 waves; IN-BLOCK t-SPLIT x2: wave w = (ts = w>>3 t-half,
// wq = w&7 s-quadrant). 256 s-rows/block; half ts processes tiles
// [16ts,16ts+16) with an independent online softmax; EXACT fp32 merge
// in-block at the end (2 rounds of 32KB reusing sV, stride-33 pad).
// Grid (8,32)=256 blocks — same block count and SAME per-block read set as
// R3 (R2 lesson: block-level split tripled FETCH; in-block split doesn't).
// R5 lesson: 65us = 32 latency rounds x ~4.9K cyc; this halves rounds (16)
// and doubles waves/CU (16). V single-buffered per half: 2 x 16.6KB = 33.3KB
// (R1 lesson: dbuf x 2 halves = 70KB > 64KB static cap).
//
// O^T orientation (R3): PV computes D[m=d][n=s], A = Vt (staged), B = P^T
// built in-register via 16 cvt_pkrtz + 8 v_permlane32_swap_b32 (T12); no sP,
// per-lane alpha/linv. St 2-PASS dual accumulator chains (Vh*Ksh, Vh*Ksl);
// V-lo dropped (fp16 logit noise < 0.119 budget). Ballot-skip dead tiles.
// ============================================================================
#define CSA 520             // (64+1)*8 u16
#define VA  (8 * CSA)       // one V array: 4160 u16

__global__ __launch_bounds__(1024, 4)
void attn_mfma(const u16* __restrict__ Kh, const u16* __restrict__ Kl,
               const u16* __restrict__ Vh, const u16* __restrict__ Vt,
               u16* __restrict__ Obuf)
{
    __shared__ u16 sV[4 * VA + 512];    // [ts][Vh | Vt]; merge: 256x33 fp32
    __shared__ float Mb[256], Lb[256];

    const int tid = threadIdx.x;
    const int w = tid >> 6, l31 = tid & 31, hh = (tid >> 5) & 1;
    const int wq = w & 7, ts = w >> 3;  // s-quadrant / t-half
    const int bh = blockIdx.y;
    const int sbase = blockIdx.x * 256 + (wq << 5);
    const int sg = sbase + l31;
    const int vb = ts * (2 * VA);       // this half's staged-V base

    // K fragments (SC2 pre-folded): B[n=s][k=d], hi/lo, loop-invariant
    f16x8 kfh[4], kfl[4];
    {
        const size_t kb = ((size_t)bh * S_ + sg) * D_;
#pragma unroll
        for (int ks = 0; ks < 4; ++ks) {
            const int db = (ks << 4) + (hh << 3);
            kfh[ks] = *(const f16x8*)(Kh + kb + db);
            kfl[ks] = *(const f16x8*)(Kl + kb + db);
        }
    }

    f32x16 oacc[2];                     // O^T: row d = ROWMAP+32nt, col s = l31
#pragma unroll
    for (int r = 0; r < 16; ++r) { oacc[0][r] = 0.f; oacc[1][r] = 0.f; }
    float m_i = -INFINITY, l_i = 0.f;

    // staging: thread's half = ts (tid>>9 == w>>3); 512 thr stage one tile
    const int sidx = tid & 511;
    const int rr = sidx >> 3, cc = sidx & 7;   // row 0..63, chunk 0..7
    const size_t gn = ((size_t)bh * S_ + rr) * D_ + (cc << 3);
    const size_t gt = ((size_t)bh * D_ + rr) * S_ + (cc << 3);
    const int slo = cc * CSA + rr * 8;

    f16x8 pv[2];
    auto load_tile = [&](int it2) {            // own half's tile
        const size_t t0 = (size_t)((ts << 4) + it2) << 6;
        pv[0] = *(const f16x8*)(Vh + gn + t0 * D_);
        pv[1] = *(const f16x8*)(Vt + gt + t0);
    };

    load_tile(0);
    for (int it = 0; it < 16; ++it) {
        *(f16x8*)&sV[vb + slo] = pv[0];
        *(f16x8*)&sV[vb + VA + slo] = pv[1];
        __syncthreads();
        if (it + 1 < 16) load_tile(it + 1);    // global->reg prefetch

        // St[t][s] = sum_d V[t][d]*Ks[s][d]  (2-pass, dual chains)
        f32x16 sta[2], stb[2];
#pragma unroll
        for (int r = 0; r < 16; ++r) {
            sta[0][r] = 0.f; sta[1][r] = 0.f;
            stb[0][r] = 0.f; stb[1][r] = 0.f;
        }
#pragma unroll
        for (int ks = 0; ks < 4; ++ks) {
            const int ch = (ks << 1) + hh;
#pragma unroll
            for (int mt = 0; mt < 2; ++mt) {
                const f16x8 av = *(const f16x8*)&sV[vb + ch * CSA + ((mt << 5) + l31) * 8];
                sta[mt] = mfma_h(av, kfh[ks], sta[mt]);
                stb[mt] = mfma_h(av, kfl[ks], stb[mt]);
            }
        }
#pragma unroll
        for (int mt = 0; mt < 2; ++mt)
#pragma unroll
            for (int r = 0; r < 16; ++r) sta[mt][r] += stb[mt][r];

        // Online softmax (base 2) over t for col s = l31
        float tmax = -INFINITY;
#pragma unroll
        for (int mt = 0; mt < 2; ++mt)
#pragma unroll
            for (int r = 0; r < 16; ++r) tmax = fmaxf(tmax, sta[mt][r]);
        tmax = fmaxf(tmax, __shfl_xor(tmax, 32));
        const float mnew = fmaxf(m_i, tmax);
        const float alpha = __builtin_amdgcn_exp2f(m_i - mnew);  // first tile: 0
        m_i = mnew;
        const unsigned long long cmask = __ballot(tmax >= mnew - 30.f);

        if (cmask) {
            float rsum = 0.f;
#pragma unroll
            for (int mt = 0; mt < 2; ++mt)
#pragma unroll
                for (int r = 0; r < 16; ++r) {
                    const float p = __builtin_amdgcn_exp2f(sta[mt][r] - mnew);
                    sta[mt][r] = p;
                    rsum += p;
                }
            rsum += __shfl_xor(rsum, 32);
            l_i = l_i * alpha + rsum;

            // alpha rescale: per-lane (oacc col = s = l31)
#pragma unroll
            for (int r = 0; r < 16; ++r) { oacc[0][r] *= alpha; oacc[1][r] *= alpha; }

            // pack P to fp16: pa[mt][q] = (t0,t0+1), pb = (t0+2,t0+3),
            // t0 = 32mt+8q+4hh (own hh)
            unsigned pa[2][4], pb[2][4];
#pragma unroll
            for (int mt = 0; mt < 2; ++mt)
#pragma unroll
                for (int q = 0; q < 4; ++q) {
                    pa[mt][q] = pkrtz(sta[mt][4 * q + 0], sta[mt][4 * q + 1]);
                    pb[mt][q] = pkrtz(sta[mt][4 * q + 2], sta[mt][4 * q + 3]);
                }

            // PV: O^T[d][s] += Vt[d][t] * P^T[t][s], 4 chunks of K=16
#pragma unroll
            for (int ks = 0; ks < 4; ++ks) {
                const int mt = ks >> 1, kk = ks & 1;
                unsigned w0 = pa[mt][2 * kk], w2v = pa[mt][2 * kk + 1];
                pl32swap(w0, w2v);
                unsigned w1 = pb[mt][2 * kk], w3v = pb[mt][2 * kk + 1];
                pl32swap(w1, w3v);
                union { unsigned u[4]; f16x8 v; } bw;
                bw.u[0] = w0; bw.u[1] = w1; bw.u[2] = w2v; bw.u[3] = w3v;
                const int ch = (ks << 1) + hh;
#pragma unroll
                for (int nt = 0; nt < 2; ++nt) {
                    const f16x8 vtf = *(const f16x8*)&sV[vb + VA + ch * CSA + ((nt << 5) + l31) * 8];
                    oacc[nt] = mfma_h(vtf, bw.v, oacc[nt]);
                }
            }
        }
        __syncthreads();   // reads done before next tile overwrites sV
    }

    // ---- exact fp32 t-split merge, half1 -> half0 (2 rounds, reuse sV) ----
    const int sl = (wq << 5) + l31;            // s_local 0..255 (per-lane)
    if (ts == 1 && hh == 0) { Mb[sl] = m_i; Lb[sl] = l_i; }
    float* red = (float*)sV;                   // 256 x 33 fp32 = 33.8KB
    float a0 = 1.f, a1 = 0.f;
#pragma unroll
    for (int nt = 0; nt < 2; ++nt) {
        __syncthreads();                       // prior sV/red reads done; Mb visible
        if (ts == 1) {
#pragma unroll
            for (int r = 0; r < 16; ++r)
                red[sl * 33 + ROWMAP(r, hh)] = oacc[nt][r];
        }
        __syncthreads();
        if (ts == 0) {
            if (nt == 0) {
                const float m1 = Mb[sl], l1 = Lb[sl];
                const float mm = fmaxf(m_i, m1);
                a0 = __builtin_amdgcn_exp2f(m_i - mm);
                a1 = __builtin_amdgcn_exp2f(m1 - mm);
                l_i = l_i * a0 + l1 * a1;
            }
#pragma unroll
            for (int r = 0; r < 16; ++r)
                oacc[nt][r] = oacc[nt][r] * a0 + red[sl * 33 + ROWMAP(r, hh)] * a1;
        }
    }
    if (ts != 0) return;

    // Epilogue: per-lane normalize, store O fp16 [M,E]
    const float linv = (l_i > 0.f) ? (1.0f / l_i) : 0.f;
    const int b = bh >> 4;
    const int hd = bh & 15;
    u16* Or = Obuf + ((size_t)b * S_ + sg) * E_ + (hd << 6);
#pragma unroll
    for (int nt = 0; nt < 2; ++nt)
#pragma unroll
        for (int q = 0; q < 4; ++q) {
            const int d0 = (nt << 5) + (q << 3) + (hh << 2);
            u16 c[4];
#pragma unroll
            for (int j = 0; j < 4; ++j)
                c[j] = f16bits((f16)(oacc[nt][4 * q + j] * linv));
            *(uint2*)&Or[d0] = make_uint2(pack2(c[0], c[1]), pack2(c[2], c[3]));
        }
}

// ============================================================================
// Workspace (~58 MB):
//   0M Xh | 8M Xl (aliased by Obuf after gemm_kv) | 16M Wkh | 18M Wkl
//   20M Wvh | 22M Wvl | 24M Woh | 26M Kh | 34M Kl | 42M Vh | 50M Vt
// ============================================================================
extern "C" void kernel_launch(void* const* d_in, const int* in_sizes, int n_in,
                              void* d_out, int out_size, void* d_ws, size_t ws_size,
                              hipStream_t stream)
{
    (void)in_sizes; (void)n_in; (void)out_size; (void)ws_size;
    const float* x  = (const float*)d_in[0];
    // d_in[1] = Wq: computed-but-unused in reference; skipped.
    const float* Wk = (const float*)d_in[2];
    const float* Wv = (const float*)d_in[3];
    const float* Wo = (const float*)d_in[4];
    float* out = (float*)d_out;

    char* ws = (char*)d_ws;
    const size_t MB = 1u << 20;
    u16* Xh  = (u16*)(ws + 0 * MB);
    u16* Xl  = (u16*)(ws + 8 * MB);
    u16* Wkh = (u16*)(ws + 16 * MB);
    u16* Wkl = (u16*)(ws + 18 * MB);
    u16* Wvh = (u16*)(ws + 20 * MB);
    u16* Wvl = (u16*)(ws + 22 * MB);
    u16* Woh = (u16*)(ws + 24 * MB);
    u16* Kh  = (u16*)(ws + 26 * MB);
    u16* Kl  = (u16*)(ws + 34 * MB);
    u16* Vh  = (u16*)(ws + 42 * MB);
    u16* Vt  = (u16*)(ws + 50 * MB);
    u16* Obuf = Xl;        // x-lo dead after gemm_kv

    convert_split<<<7168, 256, 0, stream>>>(x, Wk, Wv, Wo,
                                            Xh, Xl, Wkh, Wkl, Wvh, Wvl, Woh);
    gemm_f<0><<<dim3(E_ / 128, M_ / 128), 1024, 0, stream>>>(
        Xh, Xl, Wkh, Wkl, Wvh, Wvl, Kh, Kl, Vh, Vt, nullptr);
    attn_mfma<<<dim3(S_ / 256, B_ * H_), 1024, 0, stream>>>(Kh, Kl, Vh, Vt, Obuf);
    gemm_f<1><<<dim3(E_ / 128, M_ / 128), 1024, 0, stream>>>(
        Obuf, Obuf, Woh, Woh, Woh, Woh,
        nullptr, nullptr, nullptr, nullptr, out);
}

// Round 7
// 209.674 us; speedup vs baseline: 1.5387x; 1.5387x over previous
//
#include <hip/hip_runtime.h>
#include <math.h>

// Problem constants (fixed by reference)
#define B_ 2
#define S_ 2048
#define E_ 1024
#define H_ 16
#define D_ 64
#define M_ (B_ * S_)
// HEAD_DIM * -0.5 = -32 (faithful source bug) folded with 1/ln2 (exp2-domain
// softmax). Folded into Wk at convert time.
#define SC2 (-46.166241308446828f)

typedef unsigned short u16;
typedef _Float16 f16;
typedef __attribute__((ext_vector_type(8))) _Float16 f16x8;   // 4 VGPRs
typedef __attribute__((ext_vector_type(2))) __fp16 fp16x2_n;  // builtin ret type
typedef __attribute__((ext_vector_type(16))) float f32x16;    // 32x32 MFMA acc

static __device__ __forceinline__ f32x16 mfma_h(f16x8 a, f16x8 b, f32x16 c) {
    return __builtin_amdgcn_mfma_f32_32x32x16_f16(a, b, c, 0, 0, 0);
}
static __device__ __forceinline__ u16 f16bits(f16 h) {
    union { f16 h; u16 u; } c; c.h = h; return c.u;
}
static __device__ __forceinline__ unsigned pack2(u16 a, u16 b) {
    return (unsigned)a | ((unsigned)b << 16);
}
// One v_cvt_pkrtz_f16_f32: packs two floats to two fp16 (RTZ; P in [0,1]).
static __device__ __forceinline__ unsigned pkrtz(float a, float b) {
    fp16x2_n h = __builtin_amdgcn_cvt_pkrtz(a, b);
    unsigned u; __builtin_memcpy(&u, &h, 4); return u;
}
// v_permlane32_swap_b32: new a[32:63] = old b[0:31]; new b[0:31] = old a[32:63].
static __device__ __forceinline__ void pl32swap(unsigned &a, unsigned &b) {
    asm volatile("v_permlane32_swap_b32 %0, %1" : "+v"(a), "+v"(b));
}
#define ROWMAP(r, hh) (((r) & 3) + ((((r) >> 2)) << 3) + ((hh) << 2))

// ============================================================================
// One-shot fp32 -> fp16 hi (+ lo-residual where needed). SC2 folded into Wk.
// x, Wk, Wv: hi+lo. Wo: hi only (final GEMM is hi-only).
// ============================================================================
__global__ __launch_bounds__(256)
void convert_split(const float* __restrict__ x, const float* __restrict__ Wk,
                   const float* __restrict__ Wv, const float* __restrict__ Wo,
                   u16* __restrict__ Xh, u16* __restrict__ Xl,
                   u16* __restrict__ Wkh, u16* __restrict__ Wkl,
                   u16* __restrict__ Wvh, u16* __restrict__ Wvl,
                   u16* __restrict__ Woh)
{
    const int blk = blockIdx.x;
    const float* src; u16 *dh, *dl; int base; float sc = 1.0f; bool wantlo = true;
    if (blk < 4096)      { src = x;  dh = Xh;  dl = Xl;  base = blk; }
    else if (blk < 5120) { src = Wk; dh = Wkh; dl = Wkl; base = blk - 4096; sc = SC2; }
    else if (blk < 6144) { src = Wv; dh = Wvh; dl = Wvl; base = blk - 5120; }
    else                 { src = Wo; dh = Woh; dl = Woh; base = blk - 6144; wantlo = false; }
    const size_t off = ((size_t)base * 256 + threadIdx.x) * 4;
    const float4 v = *(const float4*)(src + off);
    const float f[4] = {v.x * sc, v.y * sc, v.z * sc, v.w * sc};
    u16 h4[4], l4[4];
#pragma unroll
    for (int i = 0; i < 4; ++i) {
        const f16 h = (f16)f[i];
        h4[i] = f16bits(h);
        l4[i] = f16bits((f16)(f[i] - (float)h));
    }
    *(uint2*)(dh + off) = make_uint2(pack2(h4[0], h4[1]), pack2(h4[2], h4[3]));
    if (wantlo)
        *(uint2*)(dl + off) = make_uint2(pack2(l4[0], l4[1]), pack2(l4[2], l4[3]));
}

// ============================================================================
// GEMM C = A @ W^T, 32x32x16 fp16 MFMA, hi/lo fp16 inputs.
// MODE 0: fused K+V projection, 3-pass split each (fp32-grade); outputs
//         Kh/Kl (fp16 hi/lo, SC2 pre-folded), Vh [B,H,S,D], Vt [B,H,D,S].
//         BK=64: 6 staged arrays = 99KB DYNAMIC LDS (> 64KB static cap;
//         gfx950 allows 160KB/wg via hipFuncSetAttribute). 16 rounds.
// MODE 1: O @ Wo^T, hi-only, fp32 out [M,E]. BK=128: 2 arrays = 66KB
//         dynamic LDS, 8 rounds.
// R5/R6 lesson: both MODEs ran 65us regardless of work per round ->
// round-count-bound (fixed ~5K cyc serial chain per barrier round).
// Halve/quarter the rounds at constant traffic.
// 1024 thr / 16 waves, __launch_bounds__(1024,4) (VGPR<=128; kernel uses
// ~60-75). Wave layout: 4m x 2n quadrants of 32x64 x 2-way K-SPLIT (ws),
// fp32 merge via LDS. Register prefetch of tile k+1. Grid (8,32)=256 blocks.
// ============================================================================
#define CSB 1032            // (128+1)*8 u16 chunk stride (pad -> spread banks)

template<int MODE>
__global__ __launch_bounds__(1024, 4)
void gemm_f(const u16* __restrict__ Ah_, const u16* __restrict__ Al_,
            const u16* __restrict__ Bkh_, const u16* __restrict__ Bkl_,
            const u16* __restrict__ Bvh_, const u16* __restrict__ Bvl_,
            u16* __restrict__ Khg, u16* __restrict__ Klg,
            u16* __restrict__ Vhg, u16* __restrict__ Vtg,
            float* __restrict__ Cout)
{
    constexpr int BK   = (MODE == 0 ? 64 : 128);
    constexpr int NCH  = BK / 8;                // 8 or 16 chunks
    constexpr int NKK  = NCH / 4;               // 2 or 4 per wave-half
    constexpr int ARRX = NCH * CSB;             // 8256 or 16512 u16
    constexpr int NARR = (MODE == 0 ? 6 : 2);
    constexpr int NIT  = E_ / BK;               // 16 or 8
    extern __shared__ u16 stage[];              // NARR*ARRX u16 (99KB / 66KB)

    const int tid = threadIdx.x;
    const int w = tid >> 6, l31 = tid & 31, hh = (tid >> 5) & 1;
    const int wt = w & 7, ws = w >> 3;          // 4m x 2n quadrant / k-split half
    const int wm = (wt >> 1) << 5, wn = (wt & 1) << 6;
    const int m0 = blockIdx.y * 128, n0 = blockIdx.x * 128;
    const int ch8 = (ws << 1) + hh;             // wave-half's base k-subchunk

    // staging: rows 0..127 (tid>>3), chunks 0..7 (tid&7); MODE 1 also +8.
    const int sr = tid >> 3, sch = tid & 7;
    const size_t gA = (size_t)(m0 + sr) * E_ + (sch << 3);
    const size_t gB = (size_t)(n0 + sr) * E_ + (sch << 3);
    const int slo = sch * CSB + sr * 8;

    f32x16 acc1[2], acc2[2];
#pragma unroll
    for (int nt = 0; nt < 2; ++nt)
#pragma unroll
        for (int r = 0; r < 16; ++r) {
            acc1[nt][r] = 0.f;
            if constexpr (MODE == 0) acc2[nt][r] = 0.f;
        }

    constexpr int NPF = (MODE == 0 ? 6 : 4);
    f16x8 pf[NPF];
    auto load_tile = [&](int k0) {
        if constexpr (MODE == 0) {
            pf[0] = *(const f16x8*)(Ah_ + gA + k0);
            pf[1] = *(const f16x8*)(Al_ + gA + k0);
            pf[2] = *(const f16x8*)(Bkh_ + gB + k0);
            pf[3] = *(const f16x8*)(Bkl_ + gB + k0);
            pf[4] = *(const f16x8*)(Bvh_ + gB + k0);
            pf[5] = *(const f16x8*)(Bvl_ + gB + k0);
        } else {
            pf[0] = *(const f16x8*)(Ah_ + gA + k0);
            pf[1] = *(const f16x8*)(Ah_ + gA + k0 + 64);
            pf[2] = *(const f16x8*)(Bkh_ + gB + k0);
            pf[3] = *(const f16x8*)(Bkh_ + gB + k0 + 64);
        }
    };
    auto store_tile = [&]() {
        if constexpr (MODE == 0) {
#pragma unroll
            for (int a = 0; a < 6; ++a)
                *(f16x8*)&stage[a * ARRX + slo] = pf[a];
        } else {
            *(f16x8*)&stage[slo] = pf[0];
            *(f16x8*)&stage[(sch + 8) * CSB + sr * 8] = pf[1];
            *(f16x8*)&stage[ARRX + slo] = pf[2];
            *(f16x8*)&stage[ARRX + (sch + 8) * CSB + sr * 8] = pf[3];
        }
    };

    load_tile(0);
    for (int it = 0; it < NIT; ++it) {
        store_tile();
        __syncthreads();
        if (it + 1 < NIT) load_tile((it + 1) * BK);   // prefetch under compute

#pragma unroll
        for (int kk = 0; kk < NKK; ++kk) {
            const int co = (ch8 + (kk << 2)) * CSB;
            const int offx = co + (wm + l31) * 8;
            const f16x8 xh = *(const f16x8*)&stage[0 * ARRX + offx];
            f16x8 xl;
            if constexpr (MODE == 0) xl = *(const f16x8*)&stage[1 * ARRX + offx];
#pragma unroll
            for (int nt = 0; nt < 2; ++nt) {
                const int ro = co + (wn + (nt << 5) + l31) * 8;
                if constexpr (MODE == 0) {
                    const f16x8 bkh = *(const f16x8*)&stage[2 * ARRX + ro];
                    const f16x8 bkl = *(const f16x8*)&stage[3 * ARRX + ro];
                    const f16x8 bvh = *(const f16x8*)&stage[4 * ARRX + ro];
                    const f16x8 bvl = *(const f16x8*)&stage[5 * ARRX + ro];
                    acc1[nt] = mfma_h(xh, bkh, acc1[nt]);
                    acc1[nt] = mfma_h(xh, bkl, acc1[nt]);
                    acc1[nt] = mfma_h(xl, bkh, acc1[nt]);
                    acc2[nt] = mfma_h(xh, bvh, acc2[nt]);
                    acc2[nt] = mfma_h(xh, bvl, acc2[nt]);
                    acc2[nt] = mfma_h(xl, bvh, acc2[nt]);
                } else {
                    const f16x8 bh = *(const f16x8*)&stage[ARRX + ro];
                    acc1[nt] = mfma_h(xh, bh, acc1[nt]);
                }
            }
        }
        __syncthreads();   // reads done before next store_tile overwrites
    }

    // K-split merge via LDS (32KB rounds: one (array,nt) per round), ws1 -> ws0.
    float* red = (float*)stage;
    constexpr int NR = (MODE == 0 ? 4 : 2);
#pragma unroll
    for (int rd = 0; rd < NR; ++rd) {
        const int ntr = rd & 1;
        f32x16* A = (MODE == 0 && rd >= 2) ? &acc2[ntr] : &acc1[ntr];
        __syncthreads();
        if (ws == 1) {
#pragma unroll
            for (int r = 0; r < 16; ++r)
                red[(wt << 10) + (r << 6) + (hh << 5) + l31] = (*A)[r];
        }
        __syncthreads();
        if (ws == 0) {
#pragma unroll
            for (int r = 0; r < 16; ++r)
                (*A)[r] += red[(wt << 10) + (r << 6) + (hh << 5) + l31];
        }
    }
    if (ws != 0) return;

    // Epilogue (ws0, 8 waves cover 128x128). C/D map: col=lane&31, row=ROWMAP.
#pragma unroll
    for (int nt = 0; nt < 2; ++nt) {
        const int n = n0 + wn + (nt << 5) + l31;
        if constexpr (MODE == 1) {
#pragma unroll
            for (int r = 0; r < 16; ++r) {
                const int m = m0 + wm + ROWMAP(r, hh);
                Cout[(size_t)m * E_ + n] = acc1[nt][r];
            }
        } else {
            const int hd = n >> 6, d = n & 63;
            const int b = m0 >> 11;             // block never crosses batch
            u16 vb16[16];
#pragma unroll
            for (int r = 0; r < 16; ++r) {
                const int s = (m0 + wm + ROWMAP(r, hh)) & (S_ - 1);
                const size_t ib = (((size_t)(b * H_ + hd) << 11) + s) * D_ + d;
                const float kv = acc1[nt][r];   // SC2 already folded
                const f16 kh = (f16)kv;
                Khg[ib] = f16bits(kh);
                Klg[ib] = f16bits((f16)(kv - (float)kh));
                const f16 vh = (f16)acc2[nt][r];
                vb16[r] = f16bits(vh);
                Vhg[ib] = vb16[r];
            }
            const size_t vtb = ((size_t)(b * H_ + hd) * D_ + d) << 11;
#pragma unroll
            for (int g = 0; g < 4; ++g) {
                const int s0 = ((m0 + wm) & (S_ - 1)) + (g << 3) + (hh << 2);
                *(uint2*)&Vtg[vtb + s0] =
                    make_uint2(pack2(vb16[4 * g], vb16[4 * g + 1]),
                               pack2(vb16[4 * g + 2], vb16[4 * g + 3]));
            }
        }
    }
}

// ============================================================================
// Attention (R3 structure, proven 64.9us; R6 lesson: 1024-thr t-split forces
// 128-VGPR cap -> 340MB spill traffic, 169us. This body needs ~160 regs ->
// must run at 2 waves/SIMD / 256-reg budget).
// logits2 = Ks@V^T, base-2 online softmax, O = P@V. All fp16.
// 512 thr / 8 waves; 256 s-rows/block; wave w owns s in [32w,32w+32).
// Grid (8,32)=256 blocks (R2 lesson: block-level split-KV tripled FETCH).
// O^T orientation: PV computes D[m=d][n=s], A = Vt (staged), B = P^T built
// in-register via 16 cvt_pkrtz + 8 v_permlane32_swap_b32 (T12); no sP,
// per-lane alpha/linv. sV double-buffered, 1 barrier/iter. St 2-PASS dual
// accumulator chains (Vh*Ksh, Vh*Ksl); V-lo dropped. Ballot-skip dead tiles.
// LDS: 2 x [Vh|Vt] = 33.3KB. Epilogue: per-lane row store (8B uint2 x 8).
// ============================================================================
#define CSA 520             // (64+1)*8 u16
#define VA  (8 * CSA)       // one V array: 4160 u16

__global__ __launch_bounds__(512, 2)
void attn_mfma(const u16* __restrict__ Kh, const u16* __restrict__ Kl,
               const u16* __restrict__ Vh, const u16* __restrict__ Vt,
               u16* __restrict__ Obuf)
{
    __shared__ u16 sV[4 * VA];          // [buf][Vh | Vt], double-buffered

    const int tid = threadIdx.x;
    const int w = tid >> 6, l31 = tid & 31, hh = (tid >> 5) & 1;
    const int bh = blockIdx.y;
    const int sbase = blockIdx.x * 256 + (w << 5);
    const int sg = sbase + l31;

    // K fragments (SC2 pre-folded): B[n=s][k=d], hi/lo, loop-invariant
    f16x8 kfh[4], kfl[4];
    {
        const size_t kb = ((size_t)bh * S_ + sg) * D_;
#pragma unroll
        for (int ks = 0; ks < 4; ++ks) {
            const int db = (ks << 4) + (hh << 3);
            kfh[ks] = *(const f16x8*)(Kh + kb + db);
            kfl[ks] = *(const f16x8*)(Kl + kb + db);
        }
    }

    f32x16 oacc[2];                     // O^T: row d = ROWMAP+32nt, col s = l31
#pragma unroll
    for (int r = 0; r < 16; ++r) { oacc[0][r] = 0.f; oacc[1][r] = 0.f; }
    float m_i = -INFINITY, l_i = 0.f;

    const int rr = tid >> 3, cc = tid & 7;     // staging: row 0..63, chunk 0..7
    const size_t gn = ((size_t)bh * S_ + rr) * D_ + (cc << 3);
    const size_t gt = ((size_t)bh * D_ + rr) * S_ + (cc << 3);
    const int slo = cc * CSA + rr * 8;

    f16x8 pv[2];
    auto load_tile = [&](int it2) {
        const size_t t0 = (size_t)it2 << 6;
        pv[0] = *(const f16x8*)(Vh + gn + t0 * D_);
        pv[1] = *(const f16x8*)(Vt + gt + t0);
    };

    load_tile(0);
    *(f16x8*)&sV[slo] = pv[0];
    *(f16x8*)&sV[VA + slo] = pv[1];
    __syncthreads();

    for (int it = 0; it < 32; ++it) {
        const int vb = (it & 1) * (2 * VA);
        const int nb = ((it + 1) & 1) * (2 * VA);
        if (it + 1 < 32) load_tile(it + 1);    // global->reg prefetch

        // St[t][s] = sum_d V[t][d]*Ks[s][d]  (2-pass, dual chains)
        f32x16 sta[2], stb[2];
#pragma unroll
        for (int r = 0; r < 16; ++r) {
            sta[0][r] = 0.f; sta[1][r] = 0.f;
            stb[0][r] = 0.f; stb[1][r] = 0.f;
        }
#pragma unroll
        for (int ks = 0; ks < 4; ++ks) {
            const int ch = (ks << 1) + hh;
#pragma unroll
            for (int mt = 0; mt < 2; ++mt) {
                const f16x8 av = *(const f16x8*)&sV[vb + ch * CSA + ((mt << 5) + l31) * 8];
                sta[mt] = mfma_h(av, kfh[ks], sta[mt]);
                stb[mt] = mfma_h(av, kfl[ks], stb[mt]);
            }
        }
#pragma unroll
        for (int mt = 0; mt < 2; ++mt)
#pragma unroll
            for (int r = 0; r < 16; ++r) sta[mt][r] += stb[mt][r];

        // Online softmax (base 2) over t for col s = l31
        float tmax = -INFINITY;
#pragma unroll
        for (int mt = 0; mt < 2; ++mt)
#pragma unroll
            for (int r = 0; r < 16; ++r) tmax = fmaxf(tmax, sta[mt][r]);
        tmax = fmaxf(tmax, __shfl_xor(tmax, 32));
        const float mnew = fmaxf(m_i, tmax);
        const float alpha = __builtin_amdgcn_exp2f(m_i - mnew);  // first tile: 0
        m_i = mnew;
        // cmask==0  =>  mnew==m_i for every lane  =>  alpha==1: skip all.
        const unsigned long long cmask = __ballot(tmax >= mnew - 30.f);

        if (cmask) {
            float rsum = 0.f;
#pragma unroll
            for (int mt = 0; mt < 2; ++mt)
#pragma unroll
                for (int r = 0; r < 16; ++r) {
                    const float p = __builtin_amdgcn_exp2f(sta[mt][r] - mnew);
                    sta[mt][r] = p;
                    rsum += p;
                }
            rsum += __shfl_xor(rsum, 32);
            l_i = l_i * alpha + rsum;

            // alpha rescale: per-lane (oacc col = s = l31)
#pragma unroll
            for (int r = 0; r < 16; ++r) { oacc[0][r] *= alpha; oacc[1][r] *= alpha; }

            // pack P to fp16: pa[mt][q] = (t0,t0+1), pb = (t0+2,t0+3),
            // t0 = 32mt+8q+4hh (own hh)
            unsigned pa[2][4], pb[2][4];
#pragma unroll
            for (int mt = 0; mt < 2; ++mt)
#pragma unroll
                for (int q = 0; q < 4; ++q) {
                    pa[mt][q] = pkrtz(sta[mt][4 * q + 0], sta[mt][4 * q + 1]);
                    pb[mt][q] = pkrtz(sta[mt][4 * q + 2], sta[mt][4 * q + 3]);
                }

            // PV: O^T[d][s] += Vt[d][t] * P^T[t][s], 4 chunks of K=16
#pragma unroll
            for (int ks = 0; ks < 4; ++ks) {
                const int mt = ks >> 1, kk = ks & 1;
                unsigned w0 = pa[mt][2 * kk], w2v = pa[mt][2 * kk + 1];
                pl32swap(w0, w2v);
                unsigned w1 = pb[mt][2 * kk], w3v = pb[mt][2 * kk + 1];
                pl32swap(w1, w3v);
                union { unsigned u[4]; f16x8 v; } bw;
                bw.u[0] = w0; bw.u[1] = w1; bw.u[2] = w2v; bw.u[3] = w3v;
                const int ch = (ks << 1) + hh;
#pragma unroll
                for (int nt = 0; nt < 2; ++nt) {
                    const f16x8 vtf = *(const f16x8*)&sV[vb + VA + ch * CSA + ((nt << 5) + l31) * 8];
                    oacc[nt] = mfma_h(vtf, bw.v, oacc[nt]);
                }
            }
        }

        if (it + 1 < 32) {                     // stage next tile into other buf
            *(f16x8*)&sV[nb + slo] = pv[0];
            *(f16x8*)&sV[nb + VA + slo] = pv[1];
        }
        __syncthreads();
    }

    // Epilogue: per-lane normalize (l_i is per-s = per-lane), store O fp16 [M,E]
    const float linv = (l_i > 0.f) ? (1.0f / l_i) : 0.f;
    const int b = bh >> 4;
    const int hd = bh & 15;
    u16* Or = Obuf + ((size_t)b * S_ + sg) * E_ + (hd << 6);
#pragma unroll
    for (int nt = 0; nt < 2; ++nt)
#pragma unroll
        for (int q = 0; q < 4; ++q) {
            const int d0 = (nt << 5) + (q << 3) + (hh << 2);
            u16 c[4];
#pragma unroll
            for (int j = 0; j < 4; ++j)
                c[j] = f16bits((f16)(oacc[nt][4 * q + j] * linv));
            *(uint2*)&Or[d0] = make_uint2(pack2(c[0], c[1]), pack2(c[2], c[3]));
        }
}

// ============================================================================
// Workspace (~58 MB):
//   0M Xh | 8M Xl (aliased by Obuf after gemm_kv) | 16M Wkh | 18M Wkl
//   20M Wvh | 22M Wvl | 24M Woh | 26M Kh | 34M Kl | 42M Vh | 50M Vt
// ============================================================================
extern "C" void kernel_launch(void* const* d_in, const int* in_sizes, int n_in,
                              void* d_out, int out_size, void* d_ws, size_t ws_size,
                              hipStream_t stream)
{
    (void)in_sizes; (void)n_in; (void)out_size; (void)ws_size;
    const float* x  = (const float*)d_in[0];
    // d_in[1] = Wq: computed-but-unused in reference; skipped.
    const float* Wk = (const float*)d_in[2];
    const float* Wv = (const float*)d_in[3];
    const float* Wo = (const float*)d_in[4];
    float* out = (float*)d_out;

    char* ws = (char*)d_ws;
    const size_t MB = 1u << 20;
    u16* Xh  = (u16*)(ws + 0 * MB);
    u16* Xl  = (u16*)(ws + 8 * MB);
    u16* Wkh = (u16*)(ws + 16 * MB);
    u16* Wkl = (u16*)(ws + 18 * MB);
    u16* Wvh = (u16*)(ws + 20 * MB);
    u16* Wvl = (u16*)(ws + 22 * MB);
    u16* Woh = (u16*)(ws + 24 * MB);
    u16* Kh  = (u16*)(ws + 26 * MB);
    u16* Kl  = (u16*)(ws + 34 * MB);
    u16* Vh  = (u16*)(ws + 42 * MB);
    u16* Vt  = (u16*)(ws + 50 * MB);
    u16* Obuf = Xl;        // x-lo dead after gemm_kv

    // Dynamic-LDS sizes: MODE 0 = 6 arrays x 8 chunks, MODE 1 = 2 x 16.
    const int lds0 = 6 * (8 * CSB) * (int)sizeof(u16);    // 99072 B
    const int lds1 = 2 * (16 * CSB) * (int)sizeof(u16);   // 66048 B
    static bool attr_done = false;
    if (!attr_done) {
        hipFuncSetAttribute(reinterpret_cast<const void*>(&gemm_f<0>),
                            hipFuncAttributeMaxDynamicSharedMemorySize, lds0);
        hipFuncSetAttribute(reinterpret_cast<const void*>(&gemm_f<1>),
                            hipFuncAttributeMaxDynamicSharedMemorySize, lds1);
        attr_done = true;
    }

    convert_split<<<7168, 256, 0, stream>>>(x, Wk, Wv, Wo,
                                            Xh, Xl, Wkh, Wkl, Wvh, Wvl, Woh);
    gemm_f<0><<<dim3(E_ / 128, M_ / 128), 1024, lds0, stream>>>(
        Xh, Xl, Wkh, Wkl, Wvh, Wvl, Kh, Kl, Vh, Vt, nullptr);
    attn_mfma<<<dim3(S_ / 256, B_ * H_), 512, 0, stream>>>(Kh, Kl, Vh, Vt, Obuf);
    gemm_f<1><<<dim3(E_ / 128, M_ / 128), 1024, lds1, stream>>>(
        Obuf, Obuf, Woh, Woh, Woh, Woh,
        nullptr, nullptr, nullptr, nullptr, out);
}